// Round 9
// baseline (254.613 us; speedup 1.0000x reference)
//
#include <hip/hip_runtime.h>

#define BB 2
#define LL 1536
#define DD 1024
#define HH 16
#define HDD 64
#define PP 1024
#define PBS 1544  // p_b row stride in shorts: 16B-aligned

typedef __attribute__((ext_vector_type(8))) __bf16 bf16x8;
typedef __attribute__((ext_vector_type(4))) float f32x4;
typedef __attribute__((ext_vector_type(2))) float f32x2;

__device__ __forceinline__ float b2f(unsigned short u) {
  unsigned int x = ((unsigned int)u) << 16;
  return __builtin_bit_cast(float, x);
}
__device__ __forceinline__ unsigned short f2b(float f) {
  unsigned int x = __builtin_bit_cast(unsigned int, f);
  unsigned int r = (x + 0x7FFFu + ((x >> 16) & 1u)) >> 16;
  return (unsigned short)r;
}
__device__ __forceinline__ unsigned int pk2(float a, float b) {
  return (unsigned int)f2b(a) | ((unsigned int)f2b(b) << 16);
}
__device__ __forceinline__ bf16x8 ldb8(const unsigned short* p) {
  return __builtin_bit_cast(bf16x8, *(const uint4*)p);
}
__device__ __forceinline__ f32x2 mk2(float a, float b) {
  f32x2 r;
  r.x = a;
  r.y = b;
  return r;
}
// async global->LDS, 16B per lane; lds dst = wave-uniform base + lane*16
__device__ __forceinline__ void gl_lds16(const unsigned short* g,
                                         unsigned short* l) {
  __builtin_amdgcn_global_load_lds(
      (const __attribute__((address_space(1))) void*)g,
      (__attribute__((address_space(3))) void*)l, 16, 0, 0);
}

// ---- DPP wave64 sum reduce (VALU-rate)
template <int CTRL>
__device__ __forceinline__ float dppadd(float x) {
  int s = __builtin_amdgcn_update_dpp(0, __builtin_bit_cast(int, x), CTRL, 0xf,
                                      0xf, true);
  return x + __builtin_bit_cast(float, s);
}
__device__ __forceinline__ float wave_sum64(float x) {
  x = dppadd<0x111>(x);  // row_shr:1
  x = dppadd<0x112>(x);  // row_shr:2
  x = dppadd<0x114>(x);  // row_shr:4
  x = dppadd<0x118>(x);  // row_shr:8
  x = dppadd<0x142>(x);  // row_bcast15
  x = dppadd<0x143>(x);  // row_bcast31
  return __builtin_bit_cast(
      float, __builtin_amdgcn_readlane(__builtin_bit_cast(int, x), 63));
}

// ---------------- prep: cast hs -> bf16 AND transpose 4x W -> WT bf16 -------
__global__ __launch_bounds__(256) void prep(
    const float* __restrict__ hs, unsigned short* __restrict__ hsb,
    const float* __restrict__ Wq, const float* __restrict__ Wk,
    const float* __restrict__ Wv, const float* __restrict__ Wo,
    unsigned short* __restrict__ WT) {
  const int bid = blockIdx.x;
  const int t = threadIdx.x;
  if (bid < 1536) {
    const int idx = bid * 2048 + t * 8;
    float4 a = *(const float4*)(hs + idx);
    float4 b = *(const float4*)(hs + idx + 4);
    uint4 u;
    u.x = pk2(a.x, a.y);
    u.y = pk2(a.z, a.w);
    u.z = pk2(b.x, b.y);
    u.w = pk2(b.z, b.w);
    *(uint4*)(hsb + idx) = u;
  } else {
    __shared__ float tile[64][68];
    const int t2 = bid - 1536;
    const int z = t2 >> 8;
    const int bx = t2 & 15, by = (t2 >> 4) & 15;
    const float* W = (z == 0) ? Wq : (z == 1) ? Wk : (z == 2) ? Wv : Wo;
    unsigned short* O = WT + (size_t)z * 1024 * 1024;
    const int r0 = by * 64;  // k rows
    const int c0 = bx * 64;  // n cols
#pragma unroll
    for (int i = 0; i < 4; ++i) {
      const int row = (t >> 4) + i * 16;
      const int col = (t & 15) * 4;
      *(float4*)&tile[row][col] =
          *(const float4*)&W[(size_t)(r0 + row) * 1024 + c0 + col];
    }
    __syncthreads();
#pragma unroll
    for (int i = 0; i < 4; ++i) {
      const int n = (t >> 4) + i * 16;
      const int k4 = (t & 15) * 4;
      uint2 u;
      u.x = pk2(tile[k4 + 0][n], tile[k4 + 1][n]);
      u.y = pk2(tile[k4 + 2][n], tile[k4 + 3][n]);
      *(uint2*)&O[(size_t)(c0 + n) * 1024 + r0 + k4] = u;
    }
  }
}

// ---------------- bf16 MFMA GEMM, 128x128 tile, BK=32, 4 waves, 4x4/wave ----
// Both operands [rows][k] bf16 (k-contiguous). "A" = M-dim operand (C rows),
// "Bt" = N-dim operand (C cols).
// MODE 0/1: TRANSPOSED compute (rows=channels from WT, cols=sequence from hs)
//   -> Q/K fragment-linear stores become contiguous uint2 (r lands on j).
// MODE 2: V untransposed (rows=seq, cols=channel), frag-linear uint2 stores.
// MODE 3: out TRANSPOSED (rows=out-channel from WoT, cols=seq from ctx),
//   float4 row-dense stores.
template <int MODE>
__device__ __forceinline__ void gemm_mfma_body(
    const unsigned short* __restrict__ A, const unsigned short* __restrict__ Bt,
    const float* __restrict__ bias, void* __restrict__ Cout, const int m0,
    const int n0) {
  __shared__ unsigned short As[128 * 32];
  __shared__ unsigned short Bs[128 * 32];
  const int t = threadIdx.x;
  const int lane = t & 63;
  const int w = t >> 6;
  const int quad = lane >> 4;
  const int lc = lane & 15;

  const int sr = lane >> 2;        // row within 16-row group
  const int sk = (lane & 3) * 8;   // k element offset
  const unsigned short* ga0 = A + (size_t)(m0 + w * 32 + sr) * 1024 + sk;
  const unsigned short* ga1 = ga0 + 16 * 1024;
  const unsigned short* gb0 = Bt + (size_t)(n0 + w * 32 + sr) * 1024 + sk;
  const unsigned short* gb1 = gb0 + 16 * 1024;
  unsigned short* la0 = As + w * 1024;
  unsigned short* la1 = As + w * 1024 + 512;
  unsigned short* lb0 = Bs + w * 1024;
  unsigned short* lb1 = Bs + w * 1024 + 512;

  const int mrow0 = (w >> 1) * 64, ncol0 = (w & 1) * 64;

  f32x4 acc[4][4];
#pragma unroll
  for (int i = 0; i < 4; ++i)
#pragma unroll
    for (int j = 0; j < 4; ++j) acc[i][j] = (f32x4){0.f, 0.f, 0.f, 0.f};

  for (int k0 = 0; k0 < 1024; k0 += 32) {
    __syncthreads();  // previous iter's ds_reads done before overwrite
    gl_lds16(ga0 + k0, la0);
    gl_lds16(ga1 + k0, la1);
    gl_lds16(gb0 + k0, lb0);
    gl_lds16(gb1 + k0, lb1);
    __syncthreads();  // staged data visible
    bf16x8 af[4], bfr[4];
#pragma unroll
    for (int i = 0; i < 4; ++i)
      af[i] = ldb8(&As[(mrow0 + i * 16 + lc) * 32 + quad * 8]);
#pragma unroll
    for (int j = 0; j < 4; ++j)
      bfr[j] = ldb8(&Bs[(ncol0 + j * 16 + lc) * 32 + quad * 8]);
#pragma unroll
    for (int i = 0; i < 4; ++i)
#pragma unroll
      for (int j = 0; j < 4; ++j)
        acc[i][j] =
            __builtin_amdgcn_mfma_f32_16x16x32_bf16(af[i], bfr[j], acc[i][j], 0, 0, 0);
  }

  if constexpr (MODE == 0 || MODE == 1) {
    // rows = channel n, cols = sequence position.
    const int hh = (m0 + mrow0) >> 6;  // head (i,quad,r add <64)
#pragma unroll
    for (int i = 0; i < 4; ++i) {
      const int nb = m0 + mrow0 + i * 16 + quad * 4;  // channel at r=0
      const float4 bz4 = *(const float4*)&bias[nb];
      const int f = ((mrow0 + i * 16) >> 5) & 1;
      const int qk = ((i * 16 + quad * 4) >> 3) & 3;
      const int j0 = (quad & 1) * 4;
#pragma unroll
      for (int jj = 0; jj < 4; ++jj) {
        const int sq = n0 + ncol0 + jj * 16 + lc;
        const int bb = (sq >= LL) ? 1 : 0;
        const int ktl = (sq - bb * LL) >> 4;  // sq&15 == lc
        float o0 = acc[i][jj][0] + bz4.x;
        float o1 = acc[i][jj][1] + bz4.y;
        float o2 = acc[i][jj][2] + bz4.z;
        float o3 = acc[i][jj][3] + bz4.w;
        if constexpr (MODE == 0) {
          o0 *= 0.125f;
          o1 *= 0.125f;
          o2 *= 0.125f;
          o3 *= 0.125f;
        }
        const size_t base =
            (((size_t)(bb * HH + hh) * 96 + ktl) * 2 + f) * 512 +
            (qk * 16 + lc) * 8 + j0;
        uint2 u;
        u.x = pk2(o0, o1);
        u.y = pk2(o2, o3);
        *(uint2*)&((unsigned short*)Cout)[base] = u;
      }
    }
  } else if constexpr (MODE == 2) {
    // untransposed: rows = sequence (key), cols = channel.
#pragma unroll
    for (int i = 0; i < 4; ++i) {
      const int row0 = m0 + mrow0 + i * 16 + quad * 4;
#pragma unroll
      for (int jj = 0; jj < 4; ++jj) {
        const int col = n0 + ncol0 + jj * 16 + lc;
        const float bz = bias[col];
        float o[4];
#pragma unroll
        for (int r = 0; r < 4; ++r) o[r] = acc[i][jj][r] + bz;
        const int bb = row0 / LL;
        const int kl = row0 - bb * LL;  // key local of r=0
        const int hh = col >> 6;
        const int hd = col & 63;
        const int hg = hd >> 4;
        const int lcv = hd & 15;
        const int tile = (kl >> 5);  // gg*2 + c
        const int qv = (kl >> 3) & 3;
        const int j0 = kl & 7;  // 0 or 4
        unsigned short* VF = (unsigned short*)Cout;
        const size_t base =
            (((size_t)(bb * HH + hh) * 4 + hg) * 48 + tile) * 512 +
            (qv * 16 + lcv) * 8 + j0;
        uint2 u;
        u.x = pk2(o[0], o[1]);
        u.y = pk2(o[2], o[3]);
        *(uint2*)&VF[base] = u;
      }
    }
  } else {
    // MODE 3: rows = out-channel n, cols = sequence -> float4 stores.
#pragma unroll
    for (int i = 0; i < 4; ++i) {
      const int nb = m0 + mrow0 + i * 16 + quad * 4;
      const float4 bz4 = *(const float4*)&bias[nb];
#pragma unroll
      for (int jj = 0; jj < 4; ++jj) {
        const int sq = n0 + ncol0 + jj * 16 + lc;
        float4 o;
        o.x = acc[i][jj][0] + bz4.x;
        o.y = acc[i][jj][1] + bz4.y;
        o.z = acc[i][jj][2] + bz4.z;
        o.w = acc[i][jj][3] + bz4.w;
        *(float4*)&((float*)Cout)[(size_t)sq * 1024 + nb] = o;
      }
    }
  }
}

__global__ __launch_bounds__(256) void qkv_gemm(
    const unsigned short* __restrict__ hsb, const unsigned short* __restrict__ WT,
    const float* __restrict__ bq, const float* __restrict__ bk,
    const float* __restrict__ bv, unsigned short* __restrict__ QF,
    unsigned short* __restrict__ KF, unsigned short* __restrict__ VF) {
  const int cb = blockIdx.x & 7;   // channel block
  const int sb = blockIdx.x >> 3;  // sequence block
  if (blockIdx.z == 0) {
    gemm_mfma_body<0>(WT, hsb, bq, QF, cb * 128, sb * 128);
  } else if (blockIdx.z == 1) {
    gemm_mfma_body<1>(WT + 1024 * 1024, hsb, bk, KF, cb * 128, sb * 128);
  } else {
    gemm_mfma_body<2>(hsb, WT + 2 * 1024 * 1024, bv, VF, sb * 128, cb * 128);
  }
}

__global__ __launch_bounds__(256) void out_gemm(
    const unsigned short* __restrict__ ctxb,
    const unsigned short* __restrict__ WoT, const float* __restrict__ bo,
    float* __restrict__ out) {
  const int cb = blockIdx.x & 7;
  const int sb = blockIdx.x >> 3;
  gemm_mfma_body<3>(WoT, ctxb, bo, out, cb * 128, sb * 128);
}

// ---------------- fused attention: scores -> softmax -> 3x diffusion -> PV ----
// One block per (b, h, 16-row q tile), 512 threads / 8 waves. (R8 body.)
__global__ __launch_bounds__(512, 4) void attn_kernel(
    const unsigned short* __restrict__ QF, const unsigned short* __restrict__ KF,
    const unsigned short* __restrict__ VF, const int* __restrict__ mask,
    const float* __restrict__ kernel_w, unsigned short* __restrict__ ctxb) {
  __shared__ __align__(16) unsigned short p_b[16][PBS];  // ~48.2 KB
  __shared__ unsigned int kvb[50];                       // packed key-valid bits
  __shared__ float red_s[8][16];

  const int t = threadIdx.x;
  const int lane = t & 63;
  const int w = t >> 6;        // wave id 0..7
  const int quad = lane >> 4;  // 0..3
  const int lc = lane & 15;
  const int b = blockIdx.z, h = blockIdx.y;
  const int q0 = blockIdx.x * 16;

  if (t < 2) kvb[48 + t] = 0;
#pragma unroll
  for (int r = 0; r < 3; ++r) {
    const int idx = r * 512 + t;
    unsigned long long bal = __ballot(mask[b * LL + idx] > 0);
    if (lane == 0) {
      const int base = (r * 512 + w * 64) >> 5;
      kvb[base] = (unsigned int)bal;
      kvb[base + 1] = (unsigned int)(bal >> 32);
    }
  }
  __syncthreads();

  // ---- phase 1: scores via transposed MFMA (A=K frags, B=Q frags).
  const unsigned short* qfb =
      QF + (((size_t)(b * HH + h) * 96 + (q0 >> 4)) * 2) * 512 + lane * 8;
  const bf16x8 qb0 = ldb8(qfb);
  const bf16x8 qb1 = ldb8(qfb + 512);
  float sc[12][4];
  const unsigned short* kfb =
      KF + (((size_t)(b * HH + h) * 96 + w) * 2) * 512 + lane * 8;
#pragma unroll
  for (int j = 0; j < 12; ++j) {
    bf16x8 ka0 = ldb8(kfb + j * 8192);
    bf16x8 ka1 = ldb8(kfb + j * 8192 + 512);
    f32x4 acc = {0.f, 0.f, 0.f, 0.f};
    acc = __builtin_amdgcn_mfma_f32_16x16x32_bf16(ka0, qb0, acc, 0, 0, 0);
    acc = __builtin_amdgcn_mfma_f32_16x16x32_bf16(ka1, qb1, acc, 0, 0, 0);
    sc[j][0] = acc[0];
    sc[j][1] = acc[1];
    sc[j][2] = acc[2];
    sc[j][3] = acc[3];
  }

  // ---- phase 2: masked softmax without max pass (shift-invariant; scores
  // bounded ~|3|).
  const int kbase = w * 16 + quad * 4;
  const int gamma = kbase >> 5;
  const int beta = kbase & 31;
  float s = 0.f;
#pragma unroll
  for (int j = 0; j < 12; ++j) {
    const unsigned int w4 = (kvb[j * 4 + gamma] >> beta) & 0xFu;
#pragma unroll
    for (int r = 0; r < 4; ++r) {
      float e = ((w4 >> r) & 1u) ? __expf(sc[j][r]) : 0.f;
      sc[j][r] = e;
      s += e;
    }
  }
  s += __shfl_xor(s, 16, 64);
  s += __shfl_xor(s, 32, 64);
  if (lane < 16) red_s[w][lane] = s;
  __syncthreads();
  float tot0 = 0.f;
#pragma unroll
  for (int ww = 0; ww < 8; ++ww) tot0 += red_s[ww][lc];
  const float inv = 1.f / tot0;
#pragma unroll
  for (int j = 0; j < 12; ++j) {
    uint2 u;
    u.x = pk2(sc[j][0] * inv, sc[j][1] * inv);
    u.y = pk2(sc[j][2] * inv, sc[j][3] * inv);
    *(uint2*)&p_b[lc][j * 128 + kbase] = u;
  }
  __syncthreads();

  // ---- phase 3: 3 diffusion steps, register-resident, f32x2 packed.
  float wr[5];
  {
    float k0 = kernel_w[0], k1 = kernel_w[1], k2 = kernel_w[2],
          k3 = kernel_w[3], k4 = kernel_w[4];
    float km = fmaxf(fmaxf(fmaxf(k0, k1), fmaxf(k2, k3)), k4);
    float e0 = __expf(k0 - km), e1 = __expf(k1 - km), e2 = __expf(k2 - km),
          e3 = __expf(k3 - km), e4 = __expf(k4 - km);
    float es = e0 + e1 + e2 + e3 + e4;
    wr[0] = e4 / es;
    wr[1] = e3 / es;
    wr[2] = e2 / es;
    wr[3] = e1 / es;
    wr[4] = e0 / es;
  }
  unsigned int db;
  {
    const int w0i = (lane * 24) >> 5, sh = (lane * 24) & 31;
    unsigned long long kw2 =
        ((unsigned long long)kvb[w0i + 1] << 32) | (unsigned long long)kvb[w0i];
    db = (unsigned int)((kw2 >> sh) & 0xFFFFFFu);
  }
  f32x2 fm2[12];
#pragma unroll
  for (int i = 0; i < 12; ++i)
    fm2[i] = mk2((float)((db >> (2 * i)) & 1u), (float)((db >> (2 * i + 1)) & 1u));

  for (int rr = 0; rr < 2; ++rr) {
    const int row = w * 2 + rr;
    f32x2 pg[12];
#pragma unroll
    for (int c = 0; c < 3; ++c) {
      uint4 v = *(const uint4*)&p_b[row][lane * 24 + c * 8];
      unsigned int ws4[4] = {v.x, v.y, v.z, v.w};
#pragma unroll
      for (int q = 0; q < 4; ++q)
        pg[c * 4 + q] =
            mk2(__builtin_bit_cast(float, ws4[q] << 16),
                __builtin_bit_cast(float, ws4[q] & 0xFFFF0000u));
    }
#pragma unroll
    for (int step = 0; step < 3; ++step) {
      float h1 = __shfl_up(pg[11].y, 1);
      float h2 = __shfl_up(pg[11].x, 1);
      float h3 = __shfl_up(pg[10].y, 1);
      float h4 = __shfl_up(pg[10].x, 1);
      if (lane == 0) h1 = h2 = h3 = h4 = 0.f;
      f32x2 ps2[12];
      ps2[0] = wr[0] * pg[0] + wr[1] * mk2(h1, pg[0].x) + wr[2] * mk2(h2, h1) +
               wr[3] * mk2(h3, h2) + wr[4] * mk2(h4, h3);
      ps2[1] = wr[0] * pg[1] + wr[1] * mk2(pg[0].y, pg[1].x) + wr[2] * pg[0] +
               wr[3] * mk2(h1, pg[0].x) + wr[4] * mk2(h2, h1);
#pragma unroll
      for (int i = 2; i < 12; ++i)
        ps2[i] = wr[0] * pg[i] + wr[1] * mk2(pg[i - 1].y, pg[i].x) +
                 wr[2] * pg[i - 1] + wr[3] * mk2(pg[i - 2].y, pg[i - 1].x) +
                 wr[4] * pg[i - 2];
      f32x2 acc2 = mk2(0.f, 0.f);
#pragma unroll
      for (int i = 0; i < 12; ++i) {
        ps2[i] *= fm2[i];
        acc2 += ps2[i];
      }
      const float tot = wave_sum64(acc2.x + acc2.y);
      const float pinv = 0.02f / (tot + 1e-9f);
#pragma unroll
      for (int i = 0; i < 12; ++i) pg[i] = 0.98f * pg[i] + ps2[i] * pinv;
    }
#pragma unroll
    for (int c = 0; c < 3; ++c) {
      uint4 u;
      u.x = pk2(pg[c * 4 + 0].x, pg[c * 4 + 0].y);
      u.y = pk2(pg[c * 4 + 1].x, pg[c * 4 + 1].y);
      u.z = pk2(pg[c * 4 + 2].x, pg[c * 4 + 2].y);
      u.w = pk2(pg[c * 4 + 3].x, pg[c * 4 + 3].y);
      *(uint4*)&p_b[row][lane * 24 + c * 8] = u;
    }
  }
  __syncthreads();

  // ---- phase 4: PV via MFMA, V frags coalesced from fragment-linear VF.
  const int cidx = (w & 3) * 16 + lc;
  const int gbase = (w >> 2) * 12;
  const unsigned short* vfb =
      VF + ((((size_t)(b * HH + h) * 4 + (w & 3)) * 48 + (w >> 2) * 24) * 512) +
      lane * 8;
  f32x4 oacc = {0.f, 0.f, 0.f, 0.f};
#pragma unroll
  for (int g = 0; g < 12; ++g) {
    const int gg = gbase + g;
#pragma unroll
    for (int c = 0; c < 2; ++c) {
      bf16x8 pa = ldb8(&p_b[lc][gg * 64 + c * 32 + quad * 8]);
      bf16x8 vf = ldb8(vfb + (g * 2 + c) * 512);
      oacc = __builtin_amdgcn_mfma_f32_16x16x32_bf16(pa, vf, oacc, 0, 0, 0);
    }
  }
  __syncthreads();  // all p_b reads done; p_b reusable as fp32 scratch
  float* pscr = (float*)&p_b[0][0];
  if (w >= 4) {
    const int idx = ((((w - 4) * 4 + quad) * 16) + lc) * 4;
    *(float4*)(pscr + idx) = make_float4(oacc[0], oacc[1], oacc[2], oacc[3]);
  }
  __syncthreads();
  if (w < 4) {
    const int idx = (((w * 4 + quad) * 16) + lc) * 4;
    float4 pr = *(const float4*)(pscr + idx);
    float o[4] = {oacc[0] + pr.x, oacc[1] + pr.y, oacc[2] + pr.z,
                  oacc[3] + pr.w};
#pragma unroll
    for (int r = 0; r < 4; ++r)
      ctxb[((size_t)(b * LL + q0 + quad * 4 + r)) * PP + h * HDD + cidx] =
          f2b(o[r]);
  }
}

extern "C" void kernel_launch(void* const* d_in, const int* in_sizes, int n_in,
                              void* d_out, int out_size, void* d_ws,
                              size_t ws_size, hipStream_t stream) {
  const float* hs = (const float*)d_in[0];
  const int* mask = (const int*)d_in[1];
  const float* Wq = (const float*)d_in[2];
  const float* bq = (const float*)d_in[3];
  const float* Wk = (const float*)d_in[4];
  const float* bk = (const float*)d_in[5];
  const float* Wv = (const float*)d_in[6];
  const float* bv = (const float*)d_in[7];
  const float* Wo = (const float*)d_in[8];
  const float* bo = (const float*)d_in[9];
  const float* kw = (const float*)d_in[10];

  const size_t NBLP = (size_t)BB * LL * PP;  // 3,145,728 elems
  unsigned short* QF = (unsigned short*)d_ws;  // Q fragment-linear
  unsigned short* KF = QF + NBLP;   // K fragment-linear
  unsigned short* VF = KF + NBLP;   // V fragment-linear
  unsigned short* ctxb = VF + NBLP; // bf16 ctx
  unsigned short* hsb = ctxb + NBLP;
  unsigned short* WT = hsb + NBLP;  // 4 x [1024][1024] bf16 (n-major)

  dim3 blk(256);
  prep<<<dim3(2560), blk, 0, stream>>>(hs, hsb, Wq, Wk, Wv, Wo, WT);
  qkv_gemm<<<dim3(192, 1, 3), blk, 0, stream>>>(hsb, WT, bq, bk, bv, QF, KF,
                                                VF);
  attn_kernel<<<dim3(96, 16, 2), dim3(512), 0, stream>>>(QF, KF, VF, mask, kw,
                                                         ctxb);
  out_gemm<<<dim3(192), blk, 0, stream>>>(ctxb, WT + 3 * 1024 * 1024, bo,
                                          (float*)d_out);
}